// Round 2
// baseline (682.834 us; speedup 1.0000x reference)
//
#include <hip/hip_runtime.h>

#define GB 8          // batch (graphs)
#define GN 4096       // nodes (2^12)
#define GH 64         // hidden
#define GE 131072     // edges per graph (2^17)
#define LN_EPS 1e-5f
#define NBIN (GB * GN)   // 32768 destination bins
#define TOTE (GB * GE)   // 1048576 total edges

// ---- presence mask: wave-per-node sum over H ----
__global__ void k_init(const float* __restrict__ nf, float* __restrict__ pres) {
    int w = (blockIdx.x * blockDim.x + threadIdx.x) >> 6;
    int lane = threadIdx.x & 63;
    if (w >= NBIN) return;
    float v = nf[(size_t)w * GH + lane];
    #pragma unroll
    for (int o = 1; o < 64; o <<= 1) v += __shfl_xor(v, o, 64);
    if (lane == 0) pres[w] = (v != 0.0f) ? 1.0f : 0.0f;
}

// ---- histogram of destinations ----
__global__ void k_hist(const int* __restrict__ ei, int* __restrict__ hist) {
    int t = blockIdx.x * blockDim.x + threadIdx.x;   // < TOTE
    int b = t >> 17, e = t & (GE - 1);
    int dst = ei[(b << 18) + GE + e];
    atomicAdd(&hist[(b << 12) + dst], 1);
}

// ---- per-graph exclusive scan of 4096 bins (256 thr x 16 bins) ----
__global__ void k_scan(const int* __restrict__ hist, int* __restrict__ off,
                       int* __restrict__ cur) {
    __shared__ int part[256];
    int b = blockIdx.x;
    int t = threadIdx.x;
    int base = (b << 12) + t * 16;
    int c[16];
    int s = 0;
    #pragma unroll
    for (int i = 0; i < 16; ++i) { c[i] = hist[base + i]; s += c[i]; }
    part[t] = s;
    __syncthreads();
    for (int o = 1; o < 256; o <<= 1) {
        int u = (t >= o) ? part[t - o] : 0;
        __syncthreads();
        part[t] += u;
        __syncthreads();
    }
    int p = b * GE + part[t] - s;   // global exclusive prefix (graph base b*GE)
    #pragma unroll
    for (int i = 0; i < 16; ++i) { off[base + i] = p; cur[base + i] = p; p += c[i]; }
    if (b == GB - 1 && t == 255) off[NBIN] = TOTE;
}

// ---- scatter edge ids into sorted order ----
__global__ void k_fill(const int* __restrict__ ei, int* __restrict__ cur,
                       int* __restrict__ sSrc, int* __restrict__ sRow) {
    int t = blockIdx.x * blockDim.x + threadIdx.x;   // < TOTE
    int b = t >> 17, e = t & (GE - 1);
    int src = ei[(b << 18) + e];
    int dst = ei[(b << 18) + GE + e];
    int pos = atomicAdd(&cur[(b << 12) + dst], 1);
    sSrc[pos] = src;
    sRow[pos] = t;                                   // t == b*GE+e == ea row id
}

// ---- h = x @ W[layer]; W staged in LDS; wave-per-row ----
__global__ void k_gemm(const float* __restrict__ x, const float* __restrict__ W,
                       float* __restrict__ h, int layer) {
    __shared__ float Wl[GH * GH];
    for (int i = threadIdx.x; i < GH * GH; i += blockDim.x)
        Wl[i] = W[layer * GH * GH + i];
    __syncthreads();
    int w = (blockIdx.x * blockDim.x + threadIdx.x) >> 6;
    int lane = threadIdx.x & 63;
    if (w >= NBIN) return;
    float xv = x[(size_t)w * GH + lane];
    float acc = 0.0f;
    #pragma unroll
    for (int k = 0; k < GH; ++k)
        acc = fmaf(__shfl(xv, k, 64), Wl[k * GH + lane], acc);
    h[(size_t)w * GH + lane] = acc;
}

// ---- wave-per-destination gather + bias + relu + LN + residual (+final blend) ----
__global__ void k_gather(const int* __restrict__ off, const int* __restrict__ sSrc,
                         const int* __restrict__ sRow,
                         const float* __restrict__ ea, const float* __restrict__ h,
                         const float* __restrict__ bias, const float* __restrict__ gam,
                         const float* __restrict__ bet,
                         float* __restrict__ x, const float* __restrict__ pres,
                         const float* __restrict__ ge, float* __restrict__ out,
                         int layer) {
    int w = (blockIdx.x * blockDim.x + threadIdx.x) >> 6;
    int lane = threadIdx.x & 63;
    if (w >= NBIN) return;
    int b = w >> 12;
    int beg = off[w], end = off[w + 1];
    const float* hb = h + (((size_t)b) << 12) * GH;
    float acc = 0.0f;
    for (int j = beg; j < end; ++j) {
        int row = sRow[j];
        int sn  = sSrc[j];
        acc = fmaf(ea[(size_t)row * GH + lane], hb[(size_t)sn * GH + lane], acc);
    }
    float v = fmaxf(acc + bias[layer * GH + lane], 0.0f);
    float s = v;
    #pragma unroll
    for (int o = 1; o < 64; o <<= 1) s += __shfl_xor(s, o, 64);
    float mu = s * (1.0f / GH);
    float d = v - mu;
    float q = d * d;
    #pragma unroll
    for (int o = 1; o < 64; o <<= 1) q += __shfl_xor(q, o, 64);
    float var = q * (1.0f / GH);
    float y = d * rsqrtf(var + LN_EPS) * gam[layer * GH + lane] + bet[layer * GH + lane];
    size_t idx = (size_t)w * GH + lane;
    if (layer > 0) y += x[idx];
    if (layer < 2) {
        x[idx] = y;
    } else {
        float p = pres[w];
        float g = ge[(size_t)(w & (GN - 1)) * GH + lane];
        out[idx] = y * p + g * (1.0f - p);
    }
}

extern "C" void kernel_launch(void* const* d_in, const int* in_sizes, int n_in,
                              void* d_out, int out_size, void* d_ws, size_t ws_size,
                              hipStream_t stream) {
    const float* nf = (const float*)d_in[0];   // node_features f32 [8,4096,64]
    const int* ei   = (const int*)d_in[1];     // edge_indices int32 [8,2,131072]
    const float* ea = (const float*)d_in[2];   // edge_attrs f32 [8,131072,64]
    const float* W  = (const float*)d_in[3];   // [3,64,64]
    const float* bb = (const float*)d_in[4];   // [3,64]
    const float* gg = (const float*)d_in[5];   // gamma [3,64]
    const float* be = (const float*)d_in[6];   // beta  [3,64]
    const float* ge = (const float*)d_in[7];   // global_emb [4096,64]
    float* out = (float*)d_out;

    float* x    = (float*)d_ws;                    // [B*N,H] f32  (8 MB)
    float* h    = x + (size_t)NBIN * GH;           // [B*N,H] f32  (8 MB)
    float* pres = h + (size_t)NBIN * GH;           // [B*N]        (128 KB)
    int* off    = (int*)(pres + NBIN);             // [NBIN+1]
    int* cur    = off + NBIN + 1;                  // [NBIN]
    int* hist   = cur + NBIN;                      // [NBIN]
    int* sSrc   = hist + NBIN;                     // [TOTE] (4 MB)
    int* sRow   = sSrc + TOTE;                     // [TOTE] (4 MB)

    hipMemsetAsync(hist, 0, NBIN * sizeof(int), stream);
    k_init<<<NBIN / 4, 256, 0, stream>>>(nf, pres);
    k_hist<<<TOTE / 256, 256, 0, stream>>>(ei, hist);
    k_scan<<<GB, 256, 0, stream>>>(hist, off, cur);
    k_fill<<<TOTE / 256, 256, 0, stream>>>(ei, cur, sSrc, sRow);

    for (int l = 0; l < 3; ++l) {
        k_gemm<<<NBIN / 4, 256, 0, stream>>>(l == 0 ? nf : x, W, h, l);
        k_gather<<<NBIN / 4, 256, 0, stream>>>(off, sSrc, sRow, ea, h, bb, gg, be,
                                               x, pres, ge, out, l);
    }
}

// Round 3
// 423.374 us; speedup vs baseline: 1.6128x; 1.6128x over previous
//
#include <hip/hip_runtime.h>

#define GB 8          // batch (graphs)
#define GN 4096       // nodes (2^12)
#define GH 64         // hidden
#define GE 131072     // edges per graph (2^17)
#define LN_EPS 1e-5f
#define NBIN (GB * GN)   // 32768 destination bins
#define TOTE (GB * GE)   // 1048576 total edges

// ---- presence mask: wave-per-node sum over H ----
__global__ void k_init(const float* __restrict__ nf, float* __restrict__ pres) {
    int w = (blockIdx.x * blockDim.x + threadIdx.x) >> 6;
    int lane = threadIdx.x & 63;
    if (w >= NBIN) return;
    float v = nf[(size_t)w * GH + lane];
    #pragma unroll
    for (int o = 1; o < 64; o <<= 1) v += __shfl_xor(v, o, 64);
    if (lane == 0) pres[w] = (v != 0.0f) ? 1.0f : 0.0f;
}

// ---- histogram of destinations ----
__global__ void k_hist(const int* __restrict__ ei, int* __restrict__ hist) {
    int t = blockIdx.x * blockDim.x + threadIdx.x;   // < TOTE
    int b = t >> 17, e = t & (GE - 1);
    int dst = ei[(b << 18) + GE + e];
    atomicAdd(&hist[(b << 12) + dst], 1);
}

// ---- per-graph exclusive scan of 4096 bins (256 thr x 16 bins) ----
__global__ void k_scan(const int* __restrict__ hist, int* __restrict__ off,
                       int* __restrict__ cur) {
    __shared__ int part[256];
    int b = blockIdx.x;
    int t = threadIdx.x;
    int base = (b << 12) + t * 16;
    int c[16];
    int s = 0;
    #pragma unroll
    for (int i = 0; i < 16; ++i) { c[i] = hist[base + i]; s += c[i]; }
    part[t] = s;
    __syncthreads();
    for (int o = 1; o < 256; o <<= 1) {
        int u = (t >= o) ? part[t - o] : 0;
        __syncthreads();
        part[t] += u;
        __syncthreads();
    }
    int p = b * GE + part[t] - s;   // global exclusive prefix (graph base b*GE)
    #pragma unroll
    for (int i = 0; i < 16; ++i) { off[base + i] = p; cur[base + i] = p; p += c[i]; }
    if (b == GB - 1 && t == 255) off[NBIN] = TOTE;
}

// ---- scatter (src, ea-row) pairs into dst-sorted order ----
__global__ void k_fill(const int* __restrict__ ei, int* __restrict__ cur,
                       int2* __restrict__ sPair) {
    int t = blockIdx.x * blockDim.x + threadIdx.x;   // < TOTE
    int b = t >> 17, e = t & (GE - 1);
    int src = ei[(b << 18) + e];
    int dst = ei[(b << 18) + GE + e];
    int pos = atomicAdd(&cur[(b << 12) + dst], 1);
    sPair[pos] = make_int2(src, t);                  // t == b*GE+e == ea row id
}

// ---- h = x @ W[layer]; W staged in LDS; wave-per-row ----
__global__ void k_gemm(const float* __restrict__ x, const float* __restrict__ W,
                       float* __restrict__ h, int layer) {
    __shared__ float Wl[GH * GH];
    for (int i = threadIdx.x; i < GH * GH; i += blockDim.x)
        Wl[i] = W[layer * GH * GH + i];
    __syncthreads();
    int w = (blockIdx.x * blockDim.x + threadIdx.x) >> 6;
    int lane = threadIdx.x & 63;
    if (w >= NBIN) return;
    float xv = x[(size_t)w * GH + lane];
    float acc = 0.0f;
    #pragma unroll
    for (int k = 0; k < GH; ++k)
        acc = fmaf(__shfl(xv, k, 64), Wl[k * GH + lane], acc);
    h[(size_t)w * GH + lane] = acc;
}

// ---- wave-per-destination gather: 4x16 lane groups, float4 lanes, MLP-rich ----
__global__ void k_gather(const int* __restrict__ off, const int2* __restrict__ sPair,
                         const float* __restrict__ ea, const float* __restrict__ h,
                         const float* __restrict__ bias, const float* __restrict__ gam,
                         const float* __restrict__ bet,
                         float* __restrict__ x, const float* __restrict__ pres,
                         const float* __restrict__ ge, float* __restrict__ out,
                         int layer) {
    int w = (blockIdx.x * blockDim.x + threadIdx.x) >> 6;
    int lane = threadIdx.x & 63;
    if (w >= NBIN) return;
    int b = w >> 12;
    int beg = off[w], end = off[w + 1];
    int cnt = end - beg;
    const float* hb = h + (((size_t)b) << 12) * GH;
    int fg = (lane & 15) << 2;    // this lane's feature quad
    int g  = lane >> 4;           // edge subgroup 0..3

    float4 acc = make_float4(0.f, 0.f, 0.f, 0.f);
    for (int base = 0; base < cnt; base += 64) {
        int n = min(cnt - base, 64);
        int2 pr = make_int2(0, 0);
        if (lane < n) pr = sPair[beg + base + lane];
        for (int j = 0; j < n; j += 8) {
            int j0 = j + g, j1 = j + 4 + g;
            int s0 = __shfl(pr.x, j0), r0 = __shfl(pr.y, j0);
            int s1 = __shfl(pr.x, j1), r1 = __shfl(pr.y, j1);
            if (j0 < n) {
                float4 ev = *reinterpret_cast<const float4*>(ea + ((size_t)r0 << 6) + fg);
                float4 hv = *reinterpret_cast<const float4*>(hb + ((size_t)s0 << 6) + fg);
                acc.x = fmaf(ev.x, hv.x, acc.x);
                acc.y = fmaf(ev.y, hv.y, acc.y);
                acc.z = fmaf(ev.z, hv.z, acc.z);
                acc.w = fmaf(ev.w, hv.w, acc.w);
            }
            if (j1 < n) {
                float4 ev = *reinterpret_cast<const float4*>(ea + ((size_t)r1 << 6) + fg);
                float4 hv = *reinterpret_cast<const float4*>(hb + ((size_t)s1 << 6) + fg);
                acc.x = fmaf(ev.x, hv.x, acc.x);
                acc.y = fmaf(ev.y, hv.y, acc.y);
                acc.z = fmaf(ev.z, hv.z, acc.z);
                acc.w = fmaf(ev.w, hv.w, acc.w);
            }
        }
    }
    // reduce across the 4 edge subgroups (lane bits 4,5)
    #pragma unroll
    for (int o = 16; o < 64; o <<= 1) {
        acc.x += __shfl_xor(acc.x, o, 64);
        acc.y += __shfl_xor(acc.y, o, 64);
        acc.z += __shfl_xor(acc.z, o, 64);
        acc.w += __shfl_xor(acc.w, o, 64);
    }
    // remap float4-per-16-lane layout -> lane = feature
    int srcl = lane >> 2;
    float c0 = __shfl(acc.x, srcl);
    float c1 = __shfl(acc.y, srcl);
    float c2 = __shfl(acc.z, srcl);
    float c3 = __shfl(acc.w, srcl);
    int cc = lane & 3;
    float v = (cc == 0) ? c0 : (cc == 1) ? c1 : (cc == 2) ? c2 : c3;

    v = fmaxf(v + bias[layer * GH + lane], 0.0f);
    float s = v;
    #pragma unroll
    for (int o = 1; o < 64; o <<= 1) s += __shfl_xor(s, o, 64);
    float mu = s * (1.0f / GH);
    float d = v - mu;
    float q = d * d;
    #pragma unroll
    for (int o = 1; o < 64; o <<= 1) q += __shfl_xor(q, o, 64);
    float var = q * (1.0f / GH);
    float y = d * rsqrtf(var + LN_EPS) * gam[layer * GH + lane] + bet[layer * GH + lane];
    size_t idx = (size_t)w * GH + lane;
    if (layer > 0) y += x[idx];
    if (layer < 2) {
        x[idx] = y;
    } else {
        float p = pres[w];
        float g2 = ge[(size_t)(w & (GN - 1)) * GH + lane];
        out[idx] = y * p + g2 * (1.0f - p);
    }
}

extern "C" void kernel_launch(void* const* d_in, const int* in_sizes, int n_in,
                              void* d_out, int out_size, void* d_ws, size_t ws_size,
                              hipStream_t stream) {
    const float* nf = (const float*)d_in[0];   // node_features f32 [8,4096,64]
    const int* ei   = (const int*)d_in[1];     // edge_indices int32 [8,2,131072]
    const float* ea = (const float*)d_in[2];   // edge_attrs f32 [8,131072,64]
    const float* W  = (const float*)d_in[3];   // [3,64,64]
    const float* bb = (const float*)d_in[4];   // [3,64]
    const float* gg = (const float*)d_in[5];   // gamma [3,64]
    const float* be = (const float*)d_in[6];   // beta  [3,64]
    const float* ge = (const float*)d_in[7];   // global_emb [4096,64]
    float* out = (float*)d_out;

    float* x    = (float*)d_ws;                    // [B*N,H] f32  (8 MB)
    float* h    = x + (size_t)NBIN * GH;           // [B*N,H] f32  (8 MB)
    float* pres = h + (size_t)NBIN * GH;           // [B*N]
    int* off    = (int*)(pres + NBIN);             // [NBIN+1]
    int* cur    = off + NBIN + 1;                  // [NBIN]
    int* hist   = cur + NBIN;                      // [NBIN]
    int2* sPair = (int2*)(hist + NBIN);            // [TOTE] (8 MB)

    hipMemsetAsync(hist, 0, NBIN * sizeof(int), stream);
    k_init<<<NBIN / 4, 256, 0, stream>>>(nf, pres);
    k_hist<<<TOTE / 256, 256, 0, stream>>>(ei, hist);
    k_scan<<<GB, 256, 0, stream>>>(hist, off, cur);
    k_fill<<<TOTE / 256, 256, 0, stream>>>(ei, cur, sPair);

    for (int l = 0; l < 3; ++l) {
        k_gemm<<<NBIN / 4, 256, 0, stream>>>(l == 0 ? nf : x, W, h, l);
        k_gather<<<NBIN / 4, 256, 0, stream>>>(off, sPair, ea, h, bb, gg, be,
                                               x, pres, ge, out, l);
    }
}